// Round 1
// baseline (97.214 us; speedup 1.0000x reference)
//
#include <hip/hip_runtime.h>
#include <cstdint>

// CovNet BNN: out = clip(x @ sign(W1)^T + b1, ±1) @ W2^T + b2
// B=8192, IN=784, HID=4096, OUT=10.
// Strategy: f16 MFMA (sign(W1) is exact in f16), K padded 784->832 (13*64),
// m97-structure 128x128 GEMM with the tiny 2nd GEMM fused in the epilogue
// (through LDS), per-col-tile partials + reduce (no atomics -> deterministic).

#define BATCH 8192
#define IN_F  784
#define HID   4096
#define OUT_F 10
#define KP    832     // padded K = 13*64
#define NKS   13
#define BM    128
#define BN    128
#define BK    64
#define HCS   136     // hc LDS row stride (ushorts): 272B = 16B-aligned, 4-dword bank skew

typedef unsigned short u16;
typedef __attribute__((ext_vector_type(8))) _Float16 f16x8;
typedef __attribute__((ext_vector_type(4))) float    f32x4;

__device__ __forceinline__ u16 f2h(float f) {
  union { _Float16 h; u16 u; } c;
  c.h = (_Float16)f;   // RNE
  return c.u;
}

__device__ __forceinline__ void gl_lds16(const void* g, void* l) {
  __builtin_amdgcn_global_load_lds(
      (const __attribute__((address_space(1))) uint32_t*)g,
      (__attribute__((address_space(3))) uint32_t*)l, 16, 0, 0);
}

// ---------------- prep: x -> f16 (padded), W1 -> sign f16 (padded), W2 -> f16 [16][4096]
__global__ void prep_kernel(const float* __restrict__ x, const float* __restrict__ W1,
                            const float* __restrict__ W2,
                            u16* __restrict__ xh, u16* __restrict__ wh,
                            u16* __restrict__ w2h) {
  const int stride = gridDim.x * blockDim.x;
  const int gid = blockIdx.x * blockDim.x + threadIdx.x;
  for (int i = gid; i < BATCH * KP; i += stride) {
    int b = i / KP, k = i - b * KP;
    float v = (k < IN_F) ? x[b * IN_F + k] : 0.f;
    xh[i] = f2h(v);
  }
  for (int i = gid; i < HID * KP; i += stride) {
    int h = i / KP, k = i - h * KP;
    float v = 0.f;
    if (k < IN_F) {
      float w = W1[h * IN_F + k];
      v = (w > 0.f) ? 1.f : ((w < 0.f) ? -1.f : 0.f);
    }
    wh[i] = f2h(v);
  }
  for (int i = gid; i < 16 * HID; i += stride) {
    int o = i >> 12, k = i & (HID - 1);
    w2h[i] = (o < OUT_F) ? f2h(W2[o * HID + k]) : (u16)0;
  }
}

// ---------------- main fused GEMM
__global__ void __launch_bounds__(256) gemm_kernel(
    const u16* __restrict__ xh, const u16* __restrict__ wh,
    const u16* __restrict__ w2h, const float* __restrict__ b1,
    float* __restrict__ part) {
  __shared__ union {
    struct { u16 a[BM * BK]; u16 b[BN * BK]; } s1;        // 32 KiB staging
    struct { u16 hc[BM * HCS]; u16 w2[16 * 128]; } s2;    // 38 KiB epilogue
  } sm;

  const int t  = threadIdx.x;
  const int ct = blockIdx.x;   // col tile (HID), 0..31
  const int br = blockIdx.y;   // row tile (BATCH), 0..63
  const int w  = t >> 6;       // wave 0..3
  const int l  = t & 63;
  const int wm = w >> 1, wn = w & 1;
  const int g  = l >> 4, r16 = l & 15;

  // staging: thread t loads 8 contiguous f16; e = t*8 within a 32-row chunk
  const int srow = t >> 3;           // 0..31
  const int scol = (t & 7) * 8;      // 0,8,..,56
  const u16* gA = xh + (size_t)(br * BM + srow) * KP + scol;
  const u16* gB = wh + (size_t)(ct * BN + srow) * KP + scol;
  u16* ldsA = &sm.s1.a[t * 8];
  u16* ldsB = &sm.s1.b[t * 8];

  f32x4 acc[4][4] = {};

  for (int ks = 0; ks < NKS; ++ks) {
    const int k0 = ks * BK;
    __syncthreads();                       // LDS safe to overwrite
#pragma unroll
    for (int j = 0; j < 4; ++j) {
      gl_lds16(gA + (size_t)(j * 32) * KP + k0, ldsA + j * 2048);
      gl_lds16(gB + (size_t)(j * 32) * KP + k0, ldsB + j * 2048);
    }
    __syncthreads();                       // drains vmcnt before use
#pragma unroll
    for (int kk = 0; kk < 2; ++kk) {
      f16x8 af[4], bfr[4];
#pragma unroll
      for (int mi = 0; mi < 4; ++mi)
        af[mi] = *(const f16x8*)&sm.s1.a[(wm * 64 + mi * 16 + r16) * BK + kk * 32 + g * 8];
#pragma unroll
      for (int ni = 0; ni < 4; ++ni)
        bfr[ni] = *(const f16x8*)&sm.s1.b[(wn * 64 + ni * 16 + r16) * BK + kk * 32 + g * 8];
#pragma unroll
      for (int mi = 0; mi < 4; ++mi)
#pragma unroll
        for (int ni = 0; ni < 4; ++ni)
          acc[mi][ni] = __builtin_amdgcn_mfma_f32_16x16x32_f16(af[mi], bfr[ni], acc[mi][ni], 0, 0, 0);
    }
  }

  // bias per output column (C/D layout: col = lane&15, row = g*4+r)
  float b1v[4];
#pragma unroll
  for (int ni = 0; ni < 4; ++ni)
    b1v[ni] = b1[ct * BN + wn * 64 + ni * 16 + r16];

  __syncthreads();   // all frag reads of s1 complete; reuse LDS

  // stage W2 slice [16][128] (one 16B load per thread)
  gl_lds16(w2h + (size_t)(t >> 4) * HID + ct * BN + (t & 15) * 8, &sm.s2.w2[t * 8]);

  // write clipped h tile to LDS as f16
#pragma unroll
  for (int mi = 0; mi < 4; ++mi)
#pragma unroll
    for (int ni = 0; ni < 4; ++ni)
#pragma unroll
      for (int r = 0; r < 4; ++r) {
        float v = acc[mi][ni][r] + b1v[ni];
        v = fminf(fmaxf(v, -1.f), 1.f);
        sm.s2.hc[(wm * 64 + mi * 16 + g * 4 + r) * HCS + wn * 64 + ni * 16 + r16] = f2h(v);
      }
  __syncthreads();   // hc + w2 ready (barrier drains vmcnt)

  // 2nd GEMM: wave w handles out rows [w*32, w*32+32), K = 128 (this col tile)
  f32x4 acc2[2] = {};
#pragma unroll
  for (int kk = 0; kk < 4; ++kk) {
    f16x8 bf2 = *(const f16x8*)&sm.s2.w2[r16 * 128 + kk * 32 + g * 8];
#pragma unroll
    for (int mi = 0; mi < 2; ++mi) {
      f16x8 af2 = *(const f16x8*)&sm.s2.hc[(w * 32 + mi * 16 + r16) * HCS + kk * 32 + g * 8];
      acc2[mi] = __builtin_amdgcn_mfma_f32_16x16x32_f16(af2, bf2, acc2[mi], 0, 0, 0);
    }
  }

  // store per-col-tile partials: part[ct][row][16]
#pragma unroll
  for (int mi = 0; mi < 2; ++mi)
#pragma unroll
    for (int r = 0; r < 4; ++r) {
      int grow = br * BM + w * 32 + mi * 16 + g * 4 + r;
      part[((size_t)ct * BATCH + grow) * 16 + r16] = acc2[mi][r];
    }
}

// ---------------- reduce partials over 32 col tiles + b2
__global__ void reduce_kernel(const float* __restrict__ part, const float* __restrict__ b2,
                              float* __restrict__ out) {
  int i = blockIdx.x * blockDim.x + threadIdx.x;
  if (i >= BATCH * OUT_F) return;
  int b = i / OUT_F, o = i - b * OUT_F;
  float acc = b2[o];
#pragma unroll
  for (int c = 0; c < 32; ++c)
    acc += part[((size_t)c * BATCH + b) * 16 + o];
  out[i] = acc;
}

extern "C" void kernel_launch(void* const* d_in, const int* in_sizes, int n_in,
                              void* d_out, int out_size, void* d_ws, size_t ws_size,
                              hipStream_t stream) {
  const float* x  = (const float*)d_in[0];
  const float* W1 = (const float*)d_in[1];
  const float* b1 = (const float*)d_in[2];
  const float* W2 = (const float*)d_in[3];
  const float* b2 = (const float*)d_in[4];
  float* out = (float*)d_out;

  // ws layout (37.4 MB total):
  //   xh  : 8192*832 f16 = 13.6 MB
  //   wh  : 4096*832 f16 =  6.8 MB
  //   w2h : 16*4096  f16 =  0.13 MB
  //   part: 32*8192*16 f32 = 16.8 MB
  u16* xh  = (u16*)d_ws;
  u16* wh  = xh + (size_t)BATCH * KP;
  u16* w2h = wh + (size_t)HID * KP;
  float* part = (float*)(w2h + 16 * HID);

  hipLaunchKernelGGL(prep_kernel, dim3(1024), dim3(256), 0, stream, x, W1, W2, xh, wh, w2h);
  hipLaunchKernelGGL(gemm_kernel, dim3(32, 64), dim3(256), 0, stream, xh, wh, w2h, b1, part);
  hipLaunchKernelGGL(reduce_kernel, dim3((BATCH * OUT_F + 255) / 256), dim3(256), 0, stream,
                     part, b2, out);
}

// Round 2
// 74.201 us; speedup vs baseline: 1.3101x; 1.3101x over previous
//
#include <hip/hip_runtime.h>
#include <cstdint>

// CovNet BNN: out = clip(x @ sign(W1)^T + b1, ±1) @ W2^T + b2
// B=8192, IN=784, HID=4096, OUT=10.
// R2: 256x256 tile, BK=64, 8 waves, T2 swizzle (pre-swizzled global src +
// swizzled ds_read), T4 counted vmcnt(2) ring-2 chunk-grained double buffer,
// T5 setprio, raw s_barrier. Fused GEMM2 epilogue -> partials -> reduce.

#define BATCH 8192
#define IN_F  784
#define HID   4096
#define OUT_F 10
#define KP    832     // padded K = 13*64
#define NKT   13
#define BM    256
#define BN    256
#define BK    64
#define NCT   (HID / BN)   // 16 col tiles
#define HCS   264          // epilogue hc row stride (f16): 528B -> 2-way banks

typedef unsigned short u16;
typedef __attribute__((ext_vector_type(8))) _Float16 f16x8;
typedef __attribute__((ext_vector_type(4))) float    f32x4;

#define BARRIER() do { asm volatile("" ::: "memory"); \
                       __builtin_amdgcn_s_barrier();  \
                       asm volatile("" ::: "memory"); } while (0)

__device__ __forceinline__ u16 f2h(float f) {
  union { _Float16 h; u16 u; } c;
  c.h = (_Float16)f;   // RNE
  return c.u;
}

__device__ __forceinline__ void gl_lds16(const void* g, void* l) {
  __builtin_amdgcn_global_load_lds(
      (const __attribute__((address_space(1))) uint32_t*)g,
      (__attribute__((address_space(3))) uint32_t*)l, 16, 0, 0);
}

// ---------------- prep: x -> f16 (padded), W1 -> sign f16 (padded), W2 -> f16 [16][4096]
__global__ void prep_kernel(const float* __restrict__ x, const float* __restrict__ W1,
                            const float* __restrict__ W2,
                            u16* __restrict__ xh, u16* __restrict__ wh,
                            u16* __restrict__ w2h) {
  const int stride = gridDim.x * blockDim.x;
  const int gid = blockIdx.x * blockDim.x + threadIdx.x;
  for (int i = gid; i < BATCH * KP; i += stride) {
    int b = i / KP, k = i - b * KP;
    float v = (k < IN_F) ? x[b * IN_F + k] : 0.f;
    xh[i] = f2h(v);
  }
  for (int i = gid; i < HID * KP; i += stride) {
    int h = i / KP, k = i - h * KP;
    float v = 0.f;
    if (k < IN_F) {
      float w = W1[h * IN_F + k];
      v = (w > 0.f) ? 1.f : ((w < 0.f) ? -1.f : 0.f);
    }
    wh[i] = f2h(v);
  }
  for (int i = gid; i < 16 * HID; i += stride) {
    int o = i >> 12, k = i & (HID - 1);
    w2h[i] = (o < OUT_F) ? f2h(W2[o * HID + k]) : (u16)0;
  }
}

// ---------------- main fused GEMM (256x256, 8 waves, counted-vmcnt pipeline)
__global__ void __launch_bounds__(512, 2) gemm_kernel(
    const u16* __restrict__ xh, const u16* __restrict__ wh,
    const u16* __restrict__ w2h, const float* __restrict__ b1,
    float* __restrict__ part) {
  __shared__ union {
    struct { u16 A[2][BM * BK]; u16 B[2][BN * BK]; } m;   // 128 KiB main loop
    struct { u16 hc[128 * HCS]; u16 w2[16 * 256]; } e;    // ~74 KiB epilogue
  } sm;

  const int t   = threadIdx.x;
  const int ct  = blockIdx.x;   // col tile (HID), 0..15
  const int br  = blockIdx.y;   // row tile (BATCH), 0..31
  const int w   = t >> 6;       // wave 0..7
  const int l   = t & 63;
  const int wm  = w >> 2;       // 0..1  (M half)
  const int wn  = w & 3;        // 0..3  (N quarter)
  const int g   = l >> 4;
  const int r16 = l & 15;
  const int swz = (r16 & 7) << 3;   // f16-unit XOR for fragment reads

  // staging: thread t covers 16B; per 64-row chunk: row = t>>3, phys slot = t&7.
  // LDS dest is linear; swizzle applied by permuting the GLOBAL source slot.
  const int  srow  = t >> 3;                 // 0..63 within chunk
  const int  sslot = (t & 7) ^ (srow & 7);   // logical 16B slot
  const u16* gA = xh + (size_t)(br * BM) * KP + sslot * 8;
  const u16* gB = wh + (size_t)(ct * BN) * KP + sslot * 8;

  auto stageA = [&](int tile, int c) {
    gl_lds16(gA + (size_t)(c * 64 + srow) * KP + tile * BK,
             &sm.m.A[tile & 1][c * 4096 + t * 8]);
  };
  auto stageB = [&](int tile, int c) {
    gl_lds16(gB + (size_t)(c * 64 + srow) * KP + tile * BK,
             &sm.m.B[tile & 1][c * 4096 + t * 8]);
  };
  auto readA = [&](int b, int mi, int kk) -> f16x8 {
    return *(const f16x8*)&sm.m.A[b][(wm * 128 + mi * 16 + r16) * BK + ((kk * 32 + g * 8) ^ swz)];
  };
  auto readB = [&](int b, int ni, int kk) -> f16x8 {
    return *(const f16x8*)&sm.m.B[b][(wn * 64 + ni * 16 + r16) * BK + ((kk * 32 + g * 8) ^ swz)];
  };

  f32x4 acc[8][4] = {};

  // prologue: tile0 fully (8 ops), then A chunks {0,2} of tile1 (2 ops)
#pragma unroll
  for (int c = 0; c < 4; ++c) stageA(0, c);
#pragma unroll
  for (int c = 0; c < 4; ++c) stageB(0, c);
  stageA(1, 0); stageA(1, 2);
  asm volatile("s_waitcnt vmcnt(2)" ::: "memory");   // tile0 complete
  BARRIER();

  for (int tt = 0; tt < NKT; ++tt) {
    const int b = tt & 1;
    // ---- P1: compute mi 0-3 (A chunks 0,2 of buf b) ----
    if (tt + 1 < NKT) {                 // stage A{1,3}+B of t+1 into buf b^1
      stageA(tt + 1, 1); stageA(tt + 1, 3);
      stageB(tt + 1, 0); stageB(tt + 1, 1); stageB(tt + 1, 2); stageB(tt + 1, 3);
    }
    f16x8 bf[4][2], af[4][2];
#pragma unroll
    for (int ni = 0; ni < 4; ++ni)
#pragma unroll
      for (int kk = 0; kk < 2; ++kk) bf[ni][kk] = readB(b, ni, kk);
#pragma unroll
    for (int mi = 0; mi < 4; ++mi)
#pragma unroll
      for (int kk = 0; kk < 2; ++kk) af[mi][kk] = readA(b, mi, kk);
    __builtin_amdgcn_s_setprio(1);
#pragma unroll
    for (int kk = 0; kk < 2; ++kk)
#pragma unroll
      for (int mi = 0; mi < 4; ++mi)
#pragma unroll
        for (int ni = 0; ni < 4; ++ni)
          acc[mi][ni] = __builtin_amdgcn_mfma_f32_16x16x32_f16(af[mi][kk], bf[ni][kk], acc[mi][ni], 0, 0, 0);
    __builtin_amdgcn_s_setprio(0);
    BARRIER();
    // ---- P2: compute mi 4-7 (A chunks 1,3 of buf b) ----
    if (tt + 2 < NKT) { stageA(tt + 2, 0); stageA(tt + 2, 2); }  // into buf b
#pragma unroll
    for (int mi = 0; mi < 4; ++mi)
#pragma unroll
      for (int kk = 0; kk < 2; ++kk) af[mi][kk] = readA(b, mi + 4, kk);
    __builtin_amdgcn_s_setprio(1);
#pragma unroll
    for (int kk = 0; kk < 2; ++kk)
#pragma unroll
      for (int mi = 0; mi < 4; ++mi)
#pragma unroll
        for (int ni = 0; ni < 4; ++ni)
          acc[mi + 4][ni] = __builtin_amdgcn_mfma_f32_16x16x32_f16(af[mi][kk], bf[ni][kk], acc[mi + 4][ni], 0, 0, 0);
    __builtin_amdgcn_s_setprio(0);
    if (tt < NKT - 1) {
      if (tt + 2 < NKT) asm volatile("s_waitcnt vmcnt(2)" ::: "memory");  // tile t+1 ready
      else              asm volatile("s_waitcnt vmcnt(0)" ::: "memory");  // tail drain
    }
    BARRIER();
  }

  // ---- epilogue: h = clip(acc + b1), fused GEMM2 through LDS ----
  {
    int row = t >> 5, sp = t & 31;
    int ls = (sp & 24) | ((sp ^ row) & 7);   // swizzled logical slot
    gl_lds16(w2h + (size_t)row * HID + ct * BN + ls * 8, &sm.e.w2[t * 8]);
  }
  float b1v[4];
#pragma unroll
  for (int ni = 0; ni < 4; ++ni) b1v[ni] = b1[ct * BN + wn * 64 + ni * 16 + r16];

  float* partBase = part + ((size_t)ct * BATCH + br * BM) * 16;

#pragma unroll
  for (int p = 0; p < 2; ++p) {
    if (p == 1) BARRIER();               // p=0 hc reads done before overwrite
    if (wm == p) {
#pragma unroll
      for (int mi = 0; mi < 8; ++mi)
#pragma unroll
        for (int ni = 0; ni < 4; ++ni)
#pragma unroll
          for (int r = 0; r < 4; ++r) {
            float v = acc[mi][ni][r] + b1v[ni];
            v = fminf(fmaxf(v, -1.f), 1.f);
            sm.e.hc[(mi * 16 + g * 4 + r) * HCS + wn * 64 + ni * 16 + r16] = f2h(v);
          }
    }
    if (p == 0) asm volatile("s_waitcnt vmcnt(0)" ::: "memory");  // w2 landed
    BARRIER();
    f32x4 acc2 = {};
#pragma unroll
    for (int kk = 0; kk < 8; ++kk) {
      f16x8 a2 = *(const f16x8*)&sm.e.hc[(w * 16 + r16) * HCS + kk * 32 + g * 8];
      int s   = kk * 4 + g;
      int sp2 = (s & 24) | ((s ^ r16) & 7);
      f16x8 b2f = *(const f16x8*)&sm.e.w2[r16 * 256 + sp2 * 8];
      acc2 = __builtin_amdgcn_mfma_f32_16x16x32_f16(a2, b2f, acc2, 0, 0, 0);
    }
#pragma unroll
    for (int r = 0; r < 4; ++r)
      partBase[(size_t)(p * 128 + w * 16 + g * 4 + r) * 16 + r16] = acc2[r];
  }
}

// ---------------- reduce partials over 16 col tiles + b2
__global__ void reduce_kernel(const float* __restrict__ part, const float* __restrict__ b2,
                              float* __restrict__ out) {
  int i = blockIdx.x * blockDim.x + threadIdx.x;
  if (i >= BATCH * OUT_F) return;
  int b = i / OUT_F, o = i - b * OUT_F;
  float acc = b2[o];
#pragma unroll
  for (int c = 0; c < NCT; ++c)
    acc += part[((size_t)c * BATCH + b) * 16 + o];
  out[i] = acc;
}

extern "C" void kernel_launch(void* const* d_in, const int* in_sizes, int n_in,
                              void* d_out, int out_size, void* d_ws, size_t ws_size,
                              hipStream_t stream) {
  const float* x  = (const float*)d_in[0];
  const float* W1 = (const float*)d_in[1];
  const float* b1 = (const float*)d_in[2];
  const float* W2 = (const float*)d_in[3];
  const float* b2 = (const float*)d_in[4];
  float* out = (float*)d_out;

  // ws layout (~29 MB):
  //   xh  : 8192*832 f16 = 13.6 MB
  //   wh  : 4096*832 f16 =  6.8 MB
  //   w2h : 16*4096  f16 =  0.13 MB
  //   part: 16*8192*16 f32 = 8.4 MB
  u16* xh  = (u16*)d_ws;
  u16* wh  = xh + (size_t)BATCH * KP;
  u16* w2h = wh + (size_t)HID * KP;
  float* part = (float*)(w2h + 16 * HID);

  hipLaunchKernelGGL(prep_kernel, dim3(1024), dim3(256), 0, stream, x, W1, W2, xh, wh, w2h);
  hipLaunchKernelGGL(gemm_kernel, dim3(NCT, BATCH / BM), dim3(512), 0, stream,
                     xh, wh, w2h, b1, part);
  hipLaunchKernelGGL(reduce_kernel, dim3((BATCH * OUT_F + 255) / 256), dim3(256), 0, stream,
                     part, b2, out);
}